// Round 8
// baseline (378.656 us; speedup 1.0000x reference)
//
#include <hip/hip_runtime.h>
#include <hip/hip_bf16.h>

#define B_SZ 128
#define IN_CAPS 1152
#define GRID 384                      // 8 bt x 48 r; 3 tiles/block (ic = r+48k)
#define NTHR (GRID * 256)             // 98304

// hat slot (round-0 proven): [b16][n16][ep8] uints, padded
#define NSTRU 12
#define BSTRU 196
#define SLOTU (16 * BSTRU)            // 3136 uints = 12.5 KB

#define W_U4 294912                   // 16*1152*16*8 f32 / 8
#define X_U4 147456                   // 128*1152*8 f32 / 8

typedef __attribute__((ext_vector_type(8))) short bf16x8;   // MFMA A/B frag
typedef __attribute__((ext_vector_type(4))) float f32x4;    // MFMA C/D frag

__device__ __forceinline__ unsigned cvtpk(float lo, float hi) {   // HW packed cvt (RNE)
    union { __hip_bfloat162 h; unsigned u; } c;
    c.h = __float22bfloat162_rn(make_float2(lo, hi));
    return c.u;
}

__device__ __forceinline__ float dpp_sum16(float v) {
    v += __int_as_float(__builtin_amdgcn_update_dpp(0, __float_as_int(v), 0xB1, 0xF, 0xF, true));
    v += __int_as_float(__builtin_amdgcn_update_dpp(0, __float_as_int(v), 0x4E, 0xF, 0xF, true));
    v += __int_as_float(__builtin_amdgcn_update_dpp(0, __float_as_int(v), 0x124, 0xF, 0xF, true));
    v += __int_as_float(__builtin_amdgcn_update_dpp(0, __float_as_int(v), 0x128, 0xF, 0xF, true));
    return v;
}

// Accumulating grid barrier: counter only increases (no reuse race); target =
// phase * GRID. Device-scope atomics + fences (G16); requires co-residency:
// LDS 62.2 KB -> 2 blocks/CU on the 160 KB pool -> capacity 512 >= 384.
__device__ __forceinline__ void grid_sync(unsigned* bar, unsigned target) {
    __syncthreads();
    if (threadIdx.x == 0) {
        __threadfence();                       // release prior writes (device)
        atomicAdd(bar, 1u);                    // device-scope (m20)
        while (__hip_atomic_load(bar, __ATOMIC_RELAXED, __HIP_MEMORY_SCOPE_AGENT) < target)
            __builtin_amdgcn_s_sleep(2);
        __threadfence();                       // acquire
    }
    __syncthreads();
}

// W LDS: [i8][nn16][em17-pad] uint4. x LDS: [b16][i9-pad] uint4.
__device__ __forceinline__ void produce_lds(const uint4* __restrict__ wlds,
                                            const uint4* __restrict__ xlds,
                                            unsigned* __restrict__ slot,
                                            int i, int em, int q, int w)
{
    uint4 xu = {0u, 0u, 0u, 0u};
    if (q == 0) xu = xlds[em * 9 + i];    // B k>=8 rows zero: kills A garbage
    union { uint4 u; bf16x8 v; } bx; bx.u = xu;
    #pragma unroll
    for (int np = 0; np < 4; ++np) {
        const int nn = 4 * w + np;
        union { uint4 u; bf16x8 v; } ax;
        ax.u = wlds[(i * 16 + nn) * 17 + em];
        f32x4 cz = {0.f, 0.f, 0.f, 0.f};
        f32x4 d = __builtin_amdgcn_mfma_f32_16x16x32_bf16(ax.v, bx.v, cz, 0, 0, 0);
        // lane (em=b, q): e = 4q..4q+3 for capsule nn
        *(uint2*)(slot + em * BSTRU + nn * NSTRU + 2 * q) =
            (uint2){cvtpk(d[0], d[1]), cvtpk(d[2], d[3])};
    }
}

// One routing pass over this block's 3 tiles (same bt; ic = r + 48k).
// MODE 0: c=1 (scaled 1/16 in reduce). MODE 1: pr=squash(accA+B).
// MODE 2: pr=sq(accA+B)+sq(accB+B). Writes f32 partial p2[g][(b_loc*16+n)*16+e].
template<int MODE>
__device__ __forceinline__ void run_pass(
    const uint4* __restrict__ WB4, const uint4* __restrict__ XB4,
    const float* __restrict__ Bb, const float* __restrict__ accA,
    const float* __restrict__ accB, float* __restrict__ p2,
    uint4* __restrict__ wlds, uint4* __restrict__ xlds,
    unsigned* __restrict__ slots, int g, int tid)
{
    const int lane = tid & 63;
    const int w    = tid >> 6;
    const int em   = lane & 15;       // producer: A-row/b-col; consumer: n
    const int q    = lane >> 4;
    const int n    = em;
    const int b_loc = 4 * w + q;
    const int bt   = g / 48;
    const int r    = g % 48;
    const int b_glb = bt * 16 + b_loc;

    float pr[16];
    if (MODE > 0) {
        const float4* bbp = (const float4*)(Bb + (n << 4));
        const float4* ap  = (const float4*)(accA + ((size_t)b_glb << 8) + (n << 4));
        float s[16], s2 = 0.f;
        #pragma unroll
        for (int k4 = 0; k4 < 4; ++k4) {
            float4 a = ap[k4], bb = bbp[k4];
            s[4*k4+0] = a.x + bb.x; s[4*k4+1] = a.y + bb.y;
            s[4*k4+2] = a.z + bb.z; s[4*k4+3] = a.w + bb.w;
        }
        #pragma unroll
        for (int e = 0; e < 16; ++e) s2 = fmaf(s[e], s[e], s2);
        float sc = sqrtf(s2) / (1.0f + s2);
        #pragma unroll
        for (int e = 0; e < 16; ++e) pr[e] = s[e] * sc;
        if (MODE == 2) {
            const float4* ap2 = (const float4*)(accB + ((size_t)b_glb << 8) + (n << 4));
            float t[16], t2 = 0.f;
            #pragma unroll
            for (int k4 = 0; k4 < 4; ++k4) {
                float4 a = ap2[k4], bb = bbp[k4];
                t[4*k4+0] = a.x + bb.x; t[4*k4+1] = a.y + bb.y;
                t[4*k4+2] = a.z + bb.z; t[4*k4+3] = a.w + bb.w;
            }
            #pragma unroll
            for (int e = 0; e < 16; ++e) t2 = fmaf(t[e], t[e], t2);
            float sc2 = sqrtf(t2) / (1.0f + t2);
            #pragma unroll
            for (int e = 0; e < 16; ++e) pr[e] = fmaf(t[e], sc2, pr[e]);
        }
        #pragma unroll
        for (int e = 0; e < 16; ++e)
            asm volatile("" : "+v"(pr[e]));   // pin: no remat across tile loop
    }

    float acc[16];
    #pragma unroll
    for (int e = 0; e < 16; ++e) acc[e] = 0.f;

    #pragma unroll 1
    for (int k = 0; k < 3; ++k) {
        const int ic = r + 48 * k;
        const int i0 = ic * 8;
        __syncthreads();              // prev tile's slots fully consumed
        // ---- stage W slice from bf16 WB4 (contiguous 256B segments) ----
        #pragma unroll
        for (int kk = 0; kk < 8; ++kk) {
            const int idx = kk * 256 + tid;            // si = kk
            const int sem = idx & 15, snn = (idx >> 4) & 15;
            wlds[(kk * 16 + snn) * 17 + sem] =
                WB4[((size_t)snn * IN_CAPS + i0 + kk) * 16 + sem];
        }
        // ---- stage x slice ----
        if (tid < 128) {
            const int sb = tid >> 3, si = tid & 7;
            xlds[sb * 9 + si] = XB4[(size_t)(bt * 16 + sb) * IN_CAPS + i0 + si];
        }
        __syncthreads();
        produce_lds(wlds, xlds, slots, 0, em, q, w);
        #pragma unroll 1
        for (int ch = 0; ch < 8; ++ch) {
            __syncthreads();
            if (ch + 1 < 8)
                produce_lds(wlds, xlds, slots + ((ch + 1) & 1) * SLOTU, ch + 1, em, q, w);
            // ---- consume chunk ch ----
            const unsigned* rowp = slots + (ch & 1) * SLOTU + b_loc * BSTRU + n * NSTRU;
            uint4 u0 = *(const uint4*)rowp;
            uint4 u1 = *(const uint4*)(rowp + 4);
            float h[16];
            {
                unsigned uu[8] = {u0.x, u0.y, u0.z, u0.w, u1.x, u1.y, u1.z, u1.w};
                #pragma unroll
                for (int j = 0; j < 8; ++j) {
                    h[2*j]   = __uint_as_float(uu[j] << 16);
                    h[2*j+1] = __uint_as_float(uu[j] & 0xFFFF0000u);
                }
            }
            if (MODE > 0) {
                float lg = 0.f;
                #pragma unroll
                for (int e = 0; e < 16; ++e) lg = fmaf(pr[e], h[e], lg);
                float p = __expf(lg);             // |lg| small -> max-free (proven)
                float z = dpp_sum16(p);           // softmax over n = 16-lane DPP row
                float c = p * __builtin_amdgcn_rcpf(z);
                #pragma unroll
                for (int e = 0; e < 16; ++e) acc[e] = fmaf(c, h[e], acc[e]);
            } else {
                #pragma unroll
                for (int e = 0; e < 16; ++e) acc[e] += h[e];
            }
        }
    }

    // ---- per-block f32 partial: p2[g][(b_loc*16+n)*16 + e] ----
    float* pp = p2 + (size_t)g * 4096 + (b_loc * 16 + n) * 16;
    *(float4*)(pp)      = (float4){acc[0],  acc[1],  acc[2],  acc[3]};
    *(float4*)(pp + 4)  = (float4){acc[4],  acc[5],  acc[6],  acc[7]};
    *(float4*)(pp + 8)  = (float4){acc[8],  acc[9],  acc[10], acc[11]};
    *(float4*)(pp + 12) = (float4){acc[12], acc[13], acc[14], acc[15]};
}

__device__ __forceinline__ void reduce_phase(const float* __restrict__ p2,
                                             float* __restrict__ acc,
                                             float scale, int gtid)
{
    if (gtid < 32768) {
        const int bt = gtid >> 12, inner = gtid & 4095;
        const float* pp = p2 + ((size_t)bt * 48) * 4096 + inner;
        float s = 0.f;
        #pragma unroll 6
        for (int j = 0; j < 48; ++j) s += pp[(size_t)j * 4096];
        acc[gtid] = s * scale;
    }
}

__global__ __launch_bounds__(256, 2)
void caps_fused(const float* __restrict__ x, const float* __restrict__ W,
                const float* __restrict__ Bb,
                uint4* __restrict__ WB4, uint4* __restrict__ XB4,
                float* __restrict__ p2, float* __restrict__ accA,
                float* __restrict__ accB, float* __restrict__ out,
                unsigned* __restrict__ bar)
{
    __shared__ __align__(16) uint4 wlds[8 * 16 * 17];   // 34816 B
    __shared__ __align__(16) uint4 xlds[16 * 9];        //  2304 B
    __shared__ __align__(16) unsigned slots[2 * SLOTU]; // 25088 B (62.2 KB)

    const int g = blockIdx.x, tid = threadIdx.x;
    const int gtid = g * 256 + tid;

    // ---- phase C: convert W,x -> bf16 workspace (coalesced 32B->16B) ----
    for (int u = gtid; u < W_U4; u += NTHR) {
        const float4* wp = (const float4*)(W + (size_t)u * 8);
        float4 a = wp[0], b = wp[1];
        WB4[u] = (uint4){cvtpk(a.x, a.y), cvtpk(a.z, a.w), cvtpk(b.x, b.y), cvtpk(b.z, b.w)};
    }
    for (int u = gtid; u < X_U4; u += NTHR) {
        const float4* xp = (const float4*)(x + (size_t)u * 8);
        float4 a = xp[0], b = xp[1];
        XB4[u] = (uint4){cvtpk(a.x, a.y), cvtpk(a.z, a.w), cvtpk(b.x, b.y), cvtpk(b.z, b.w)};
    }
    grid_sync(bar, 1 * GRID);

    run_pass<0>(WB4, XB4, Bb, nullptr, nullptr, p2, wlds, xlds, slots, g, tid);
    grid_sync(bar, 2 * GRID);
    reduce_phase(p2, accA, 0.0625f, gtid);              // c = softmax(0) = 1/16
    grid_sync(bar, 3 * GRID);
    run_pass<1>(WB4, XB4, Bb, accA, nullptr, p2, wlds, xlds, slots, g, tid);
    grid_sync(bar, 4 * GRID);
    reduce_phase(p2, accB, 1.0f, gtid);
    grid_sync(bar, 5 * GRID);
    run_pass<2>(WB4, XB4, Bb, accA, accB, p2, wlds, xlds, slots, g, tid);
    grid_sync(bar, 6 * GRID);

    // ---- final: out[b][n][e] = squash(sum + B), thread owns a (b,n) row ----
    if (gtid < 2048) {
        const int b = gtid >> 4, n = gtid & 15;
        const int bt = b >> 4, b_loc = b & 15;
        const float* pp = p2 + ((size_t)bt * 48) * 4096 + (b_loc * 16 + n) * 16;
        float s[16];
        #pragma unroll
        for (int e = 0; e < 16; ++e) s[e] = Bb[n * 16 + e];
        for (int j = 0; j < 48; ++j) {
            const float4* rp = (const float4*)(pp + (size_t)j * 4096);
            float4 v0 = rp[0], v1 = rp[1], v2 = rp[2], v3 = rp[3];
            s[0]  += v0.x; s[1]  += v0.y; s[2]  += v0.z; s[3]  += v0.w;
            s[4]  += v1.x; s[5]  += v1.y; s[6]  += v1.z; s[7]  += v1.w;
            s[8]  += v2.x; s[9]  += v2.y; s[10] += v2.z; s[11] += v2.w;
            s[12] += v3.x; s[13] += v3.y; s[14] += v3.z; s[15] += v3.w;
        }
        float s2 = 0.f;
        #pragma unroll
        for (int e = 0; e < 16; ++e) s2 = fmaf(s[e], s[e], s2);
        float sc = sqrtf(s2) / (1.0f + s2);
        float* op = out + (size_t)gtid * 16;
        *(float4*)(op)      = (float4){s[0] * sc,  s[1] * sc,  s[2] * sc,  s[3] * sc};
        *(float4*)(op + 4)  = (float4){s[4] * sc,  s[5] * sc,  s[6] * sc,  s[7] * sc};
        *(float4*)(op + 8)  = (float4){s[8] * sc,  s[9] * sc,  s[10] * sc, s[11] * sc};
        *(float4*)(op + 12) = (float4){s[12] * sc, s[13] * sc, s[14] * sc, s[15] * sc};
    }
}

extern "C" void kernel_launch(void* const* d_in, const int* in_sizes, int n_in,
                              void* d_out, int out_size, void* d_ws, size_t ws_size,
                              hipStream_t stream)
{
    const float* x  = (const float*)d_in[0];   // [128,1152,8]
    const float* W  = (const float*)d_in[1];   // [16,1152,16,8]
    const float* Bb = (const float*)d_in[2];   // [16,16]
    float* out = (float*)d_out;                // [128,16,16] fp32

    unsigned* bar = (unsigned*)d_ws;                     // 4 B (zeroed below)
    uint4* WB4 = (uint4*)((char*)d_ws + 256);            // 4.72 MB bf16 W
    uint4* XB4 = WB4 + W_U4;                             // 2.36 MB bf16 x
    float* p2   = (float*)(XB4 + X_U4);                  // 384*16KB = 6.29 MB
    float* accA = p2 + (size_t)GRID * 4096;              // 128 KB
    float* accB = accA + 32768;                          // 128 KB

    hipMemsetAsync((void*)bar, 0, 4, stream);
    caps_fused<<<GRID, 256, 0, stream>>>(x, W, Bb, WB4, XB4, p2, accA, accB,
                                         out, bar);
}

// Round 10
// 182.060 us; speedup vs baseline: 2.0798x; 2.0798x over previous
//
#include <hip/hip_runtime.h>
#include <hip/hip_bf16.h>

#define IN_CAPS 1152

typedef __attribute__((ext_vector_type(8))) short bf16x8;   // MFMA A/B frag
typedef __attribute__((ext_vector_type(4))) float f32x4;    // MFMA C/D frag

__device__ __forceinline__ unsigned cvtpk(float lo, float hi) {   // HW packed cvt (RNE)
    union { __hip_bfloat162 h; unsigned u; } c;
    c.h = __float22bfloat162_rn(make_float2(lo, hi));
    return c.u;
}

// Pass-block decode, XCD-aware: id%8 = XCD owns ic range [xcd*18, xcd*18+18)
// for ALL bt -> per-XCD W working set = 9.4/8 = 1.2 MB f32 (L2-resident).
__device__ __forceinline__ void decode_pass(int id, int& bt, int& ic) {
    const int xcd = id & 7, j = id >> 3;     // j in [0,144)
    bt = j / 18;
    ic = xcd * 18 + j % 18;
}

// ---- routing pass, single-wave blocks (64 thr), register-resident ----
// One wave owns tile (bt, ic): 8 i's x all 16 n. Per i: 16 MFMA (A = W-frag
// cvt'd in-reg from f32, B = x-frag, k>=8 zeroed). D lane (em=b, q): holds
// hat[b][e=4q+r][nn] in f32. MODE 0: acc[nn] = MFMA-C chain (sum_i hat).
// MODE 1: logit part = sum_r d*pr (pr preloaded, 64 VGPR), q-sum via
// shfl_xor(16/32), softmax over nn IN-REGISTER, acc += c*d.
// No LDS, no barriers. Partial out: [blk][nn][q][em] bf16 pairs ->
// store addr = nn*64 + lane -> fully contiguous 512 B per nn per wave.
template<int MODE>
__global__ __launch_bounds__(64)
void caps_pass(const float* __restrict__ x, const float* __restrict__ W,
               const float* __restrict__ pr, unsigned long long* __restrict__ partial)
{
    const int lane = threadIdx.x;
    const int em = lane & 15, q = lane >> 4;
    int bt, ic; decode_pass(blockIdx.x, bt, ic);
    const int i0 = ic * 8;

    f32x4 acc[16];
    #pragma unroll
    for (int nn = 0; nn < 16; ++nn) acc[nn] = (f32x4){0.f, 0.f, 0.f, 0.f};

    float4 prv[16];
    if (MODE) {
        #pragma unroll
        for (int nn = 0; nn < 16; ++nn)   // pr[b_glb][nn][4q..4q+3], i-invariant
            prv[nn] = *(const float4*)(pr + (size_t)(bt * 16 + em) * 256 + nn * 16 + 4 * q);
    }

    #pragma unroll 1
    for (int ii = 0; ii < 8; ++ii) {
        const int i = i0 + ii;
        // B operand: x[b=em][i][0..7] f32 -> bf16; k>=8 rows zero (kills A garbage)
        uint4 xu = {0u, 0u, 0u, 0u};
        if (q == 0) {
            const float4* xp = (const float4*)(x + ((size_t)(bt * 16 + em) * IN_CAPS + i) * 8);
            float4 a = xp[0], c = xp[1];
            xu = (uint4){cvtpk(a.x, a.y), cvtpk(a.z, a.w), cvtpk(c.x, c.y), cvtpk(c.z, c.w)};
        }
        union { uint4 u; bf16x8 v; } bx; bx.u = xu;

        if (MODE == 0) {
            #pragma unroll
            for (int nn = 0; nn < 16; ++nn) {
                const float4* wp = (const float4*)(W + (((size_t)nn * IN_CAPS + i) * 16 + em) * 8);
                float4 wa = wp[0], wb = wp[1];
                union { uint4 u; bf16x8 v; } ax;
                ax.u = (uint4){cvtpk(wa.x, wa.y), cvtpk(wa.z, wa.w),
                               cvtpk(wb.x, wb.y), cvtpk(wb.z, wb.w)};
                acc[nn] = __builtin_amdgcn_mfma_f32_16x16x32_bf16(ax.v, bx.v, acc[nn], 0, 0, 0);
            }
        } else {
            f32x4 d[16];
            float part[16];
            #pragma unroll
            for (int nn = 0; nn < 16; ++nn) {
                const float4* wp = (const float4*)(W + (((size_t)nn * IN_CAPS + i) * 16 + em) * 8);
                float4 wa = wp[0], wb = wp[1];
                union { uint4 u; bf16x8 v; } ax;
                ax.u = (uint4){cvtpk(wa.x, wa.y), cvtpk(wa.z, wa.w),
                               cvtpk(wb.x, wb.y), cvtpk(wb.z, wb.w)};
                f32x4 cz = {0.f, 0.f, 0.f, 0.f};
                d[nn] = __builtin_amdgcn_mfma_f32_16x16x32_bf16(ax.v, bx.v, cz, 0, 0, 0);
                part[nn] = d[nn][0] * prv[nn].x + d[nn][1] * prv[nn].y
                         + d[nn][2] * prv[nn].z + d[nn][3] * prv[nn].w;
            }
            // q-sum (lanes em, em+16, em+32, em+48) -> full logit; softmax over nn
            float p[16], Z = 0.f;
            #pragma unroll
            for (int nn = 0; nn < 16; ++nn) {
                float t = part[nn];
                t += __shfl_xor(t, 16, 64);
                t += __shfl_xor(t, 32, 64);
                p[nn] = __expf(t);            // |lg| small -> max-free (proven R7+)
                Z += p[nn];
            }
            float rz = __builtin_amdgcn_rcpf(Z);
            #pragma unroll
            for (int nn = 0; nn < 16; ++nn) {
                float c = p[nn] * rz;
                acc[nn][0] = fmaf(c, d[nn][0], acc[nn][0]);
                acc[nn][1] = fmaf(c, d[nn][1], acc[nn][1]);
                acc[nn][2] = fmaf(c, d[nn][2], acc[nn][2]);
                acc[nn][3] = fmaf(c, d[nn][3], acc[nn][3]);
            }
        }
    }

    // partial[blk][nn*64 + lane] = bf16x4 of acc[nn] (contiguous 512 B / nn)
    unsigned long long* pp = partial + (size_t)blockIdx.x * 1024 + lane;
    #pragma unroll
    for (int nn = 0; nn < 16; ++nn) {
        union { uint2 u2; unsigned long long ll; } o;
        o.u2 = (uint2){cvtpk(acc[nn][0], acc[nn][1]), cvtpk(acc[nn][2], acc[nn][3])};
        pp[nn * 64] = o.ll;
    }
}

// ---- reduce 144 bf16 slices per bt + fused B + squash ----
// 32 blocks x 256 thr; gpos = bt*1024 + inner, inner = nn*64 + q*16 + em.
// Thread sums its 4 e's over 144 slices (8 B loads, lane-contiguous), adds B,
// squash via shfl_xor(16/32) row-sum (q lanes), emits:
// RM 1: pr0 = squash(S/16 + B).  RM 2: pr2 = pr0 + squash(S + B).
// RM 3: out = squash(S + B).
template<int RM>
__global__ __launch_bounds__(256)
void caps_reduce(const unsigned long long* __restrict__ partial,
                 const float* __restrict__ Bb, const float* __restrict__ pr_in,
                 float* __restrict__ outp)
{
    const int gpos = blockIdx.x * 256 + threadIdx.x;   // [0, 8192)
    const int bt = gpos >> 10, inner = gpos & 1023;
    const int nn = inner >> 6, q = (inner >> 4) & 3, em = inner & 15;

    float s0 = 0.f, s1 = 0.f, s2 = 0.f, s3 = 0.f;
    #pragma unroll 4
    for (int ic = 0; ic < 144; ++ic) {
        const int sid = (ic / 18) + 8 * (bt * 18 + ic % 18);   // pass-block id
        union { unsigned long long ll; uint2 u2; } u;
        u.ll = partial[(size_t)sid * 1024 + inner];
        s0 += __uint_as_float(u.u2.x << 16);
        s1 += __uint_as_float(u.u2.x & 0xFFFF0000u);
        s2 += __uint_as_float(u.u2.y << 16);
        s3 += __uint_as_float(u.u2.y & 0xFFFF0000u);
    }
    const float kf = (RM == 1) ? 0.0625f : 1.0f;       // c = softmax(0) = 1/16
    const float4 bb = *(const float4*)(Bb + nn * 16 + 4 * q);
    float v0 = fmaf(s0, kf, bb.x), v1 = fmaf(s1, kf, bb.y);
    float v2 = fmaf(s2, kf, bb.z), v3 = fmaf(s3, kf, bb.w);
    float ss = v0 * v0 + v1 * v1 + v2 * v2 + v3 * v3;
    ss += __shfl_xor(ss, 16, 64);                      // q lanes: 16-apart
    ss += __shfl_xor(ss, 32, 64);
    float sc = sqrtf(ss) / (1.0f + ss);

    const size_t off = ((size_t)(bt * 16 + em) << 8) + (nn << 4) + 4 * q;
    if (RM == 3) {
        *(float4*)(outp + off) = (float4){v0 * sc, v1 * sc, v2 * sc, v3 * sc};
    } else {
        float4 p0 = {0.f, 0.f, 0.f, 0.f};
        if (RM == 2) p0 = *(const float4*)(pr_in + off);
        *(float4*)(outp + off) = (float4){fmaf(v0, sc, p0.x), fmaf(v1, sc, p0.y),
                                          fmaf(v2, sc, p0.z), fmaf(v3, sc, p0.w)};
    }
}

extern "C" void kernel_launch(void* const* d_in, const int* in_sizes, int n_in,
                              void* d_out, int out_size, void* d_ws, size_t ws_size,
                              hipStream_t stream)
{
    const float* x  = (const float*)d_in[0];   // [128,1152,8]
    const float* W  = (const float*)d_in[1];   // [16,1152,16,8]
    const float* Bb = (const float*)d_in[2];   // [16,16]
    float* out = (float*)d_out;                // [128,16,16] fp32

    unsigned long long* partial = (unsigned long long*)d_ws;  // 1152*8KB = 9.4 MB
    float* prA = (float*)(partial + (size_t)1152 * 1024);     // 128 KB
    float* pr2 = prA + 32768;                                 // 128 KB

    caps_pass<0><<<1152, 64, 0, stream>>>(x, W, nullptr, partial);
    caps_reduce<1><<<32, 256, 0, stream>>>(partial, Bb, nullptr, prA);
    caps_pass<1><<<1152, 64, 0, stream>>>(x, W, prA, partial);
    caps_reduce<2><<<32, 256, 0, stream>>>(partial, Bb, prA, pr2);
    caps_pass<1><<<1152, 64, 0, stream>>>(x, W, pr2, partial);
    caps_reduce<3><<<32, 256, 0, stream>>>(partial, Bb, nullptr, out);
}